// Round 6
// baseline (519.680 us; speedup 1.0000x reference)
//
#include <hip/hip_runtime.h>
#include <math.h>

#define B_ 512
#define T_ 128
#define D_ 512
#define O_ 10

typedef unsigned int uint32;
typedef unsigned long long uint64;
typedef short bf16x8 __attribute__((ext_vector_type(8)));   // 8 bf16 = 4 VGPRs
typedef float f32x4 __attribute__((ext_vector_type(4)));

__device__ __forceinline__ uint32 bf16rne(float f) {
    uint32 u = __float_as_uint(f);
    return (u + 0x7FFFu + ((u >> 16) & 1u)) >> 16;
}
__device__ __forceinline__ float bf16f(uint32 h) { return __uint_as_float(h << 16); }

// packed RNE pair: low16 = bf16(lo), high16 = bf16(hi)
__device__ __forceinline__ uint32 pkbf16(float lo, float hi) {
    return bf16rne(lo) | (bf16rne(hi) << 16);
}

__device__ __forceinline__ void gload16_lds(const void* g, void* l) {
    __builtin_amdgcn_global_load_lds(
        (const __attribute__((address_space(1))) unsigned int*)g,
        (__attribute__((address_space(3))) unsigned int*)l, 16, 0, 0);
}

// ---------------- pre-split W1 into 3 bf16 planes [3][512][512] ----------------
__global__ __launch_bounds__(256)
void presplitW_kernel(const float* __restrict__ W1, unsigned short* __restrict__ Wsp)
{
    const int idx = blockIdx.x * 256 + threadIdx.x;
    const float4 v = *(const float4*)(W1 + (size_t)idx * 4);
    float vv[4] = {v.x, v.y, v.z, v.w};
    uint32 c0[4], c1[4], c2[4];
#pragma unroll
    for (int i = 0; i < 4; ++i) {
        c0[i] = bf16rne(vv[i]);
        float r = vv[i] - bf16f(c0[i]);
        c1[i] = bf16rne(r);
        float r2 = r - bf16f(c1[i]);
        c2[i] = bf16rne(r2);
    }
    const size_t base = (size_t)idx * 4;
    uint2 w;
    w.x = c0[0] | (c0[1] << 16); w.y = c0[2] | (c0[3] << 16);
    *(uint2*)(Wsp + base) = w;
    w.x = c1[0] | (c1[1] << 16); w.y = c1[2] | (c1[3] << 16);
    *(uint2*)(Wsp + 262144 + base) = w;
    w.x = c2[0] | (c2[1] << 16); w.y = c2[2] | (c2[3] << 16);
    *(uint2*)(Wsp + 524288 + base) = w;
}

// ---------------- GEMM1: bf16x3-split MFMA + fused fp64 BN partials ----------------
// R6: counted-vmcnt pipeline (T3-min + T4).
//  - Ws3 double-buffered (72 KB LDS total, 2 blocks/CU): W-DMA(k+1) issued at
//    step top, consumed next step -> a full K-step to land.
//  - RAW s_barrier (inline asm) x2 per step; NO vmcnt(0) in the loop. The
//    convert's read of A-raw regs makes the compiler emit vmcnt(6): waits
//    A(k)+W(k) (older), leaves W(k+1)'s 6 DMAs in flight. Prologue stages
//    W(0) BEFORE the A(0) loads so the age ordering holds at ks=0 too.
//  - setprio(1) around the MFMA block (T5; 2 phase-offset blocks/CU).
#define SPW 32
#define SPL (128*SPW)

__global__ __launch_bounds__(256)
void gemm1_kernel(const float* __restrict__ data, const float* __restrict__ drop,
                  const unsigned short* __restrict__ Wsp, const float* __restrict__ b1,
                  float* __restrict__ hbuf, double* __restrict__ pSum,
                  double* __restrict__ pSq, int t0, int Tc)
{
    __shared__ __align__(16) unsigned short As3[3 * SPL];        // 24 KB
    __shared__ __align__(16) unsigned short Ws3[2][3 * SPL];     // 48 KB

    const int tid = threadIdx.x;
    const int bid = blockIdx.x;
    // XCD swizzle (verified: FETCH 606->159MB)
    const int xcd = bid & 7;
    const int rest = bid >> 3;
    const int yy = rest & 3;
    const int g = (rest >> 2) * 8 + xcd;

    const int R = g * 128;
    const int tc = R >> 9;
    const int b_base = R & 511;
    const int t = t0 + tc;
    const int d0 = yy * 128;

    const int w = tid >> 6;
    const int lane = tid & 63;
    const int wm = w & 1, wn = w >> 1;
    const int q = lane >> 4, r16 = lane & 15;

    f32x4 acc[4][4];
#pragma unroll
    for (int i = 0; i < 4; ++i)
#pragma unroll
        for (int j = 0; j < 4; ++j) acc[i][j] = (f32x4){0.f, 0.f, 0.f, 0.f};

    // ---- per-thread constant staging geometry ----
    int dstA[2];
    const float* dsrc[2];
    const float* msrc[2];
#pragma unroll
    for (int i = 0; i < 2; ++i) {
        const int p = tid + i * 256;
        const int m = p >> 2;
        const int qg = p & 3;
        dstA[i] = m * SPW + (qg ^ ((m >> 1) & 3)) * 8;
        dsrc[i] = data + ((size_t)(b_base + m) * T_ + t) * D_ + qg * 8;
        msrc[i] = drop + ((size_t)t * B_ + b_base + m) * D_ + qg * 8;
    }

#define STAGE_W(K0, BUF)                                                        \
    {                                                                           \
        _Pragma("unroll")                                                       \
        for (int i_ = 0; i_ < 6; ++i_) {                                        \
            const int p_ = tid + i_ * 256;                                      \
            const int s_ = p_ >> 9;                                             \
            const int rem_ = p_ & 511;                                          \
            const int n_ = rem_ >> 2;                                           \
            const int qs_ = rem_ & 3;                                           \
            const int qg_ = qs_ ^ ((n_ >> 1) & 3);                              \
            gload16_lds(Wsp + (size_t)s_ * 262144 + (size_t)(d0 + n_) * 512     \
                            + (K0) + qg_ * 8,                                   \
                        &Ws3[BUF][(size_t)p_ * 8]);                             \
        }                                                                       \
    }

    // ---- prologue: W(0) DMA FIRST (must be older than A(0) loads) ----
    STAGE_W(0, 0);
    float4 dR[2][2], mR[2][2];
#pragma unroll
    for (int i = 0; i < 2; ++i) {
        dR[i][0] = *(const float4*)(dsrc[i]);
        dR[i][1] = *(const float4*)(dsrc[i] + 4);
        mR[i][0] = *(const float4*)(msrc[i]);
        mR[i][1] = *(const float4*)(msrc[i] + 4);
    }

    int cur = 0;
    for (int ks = 0; ks < 16; ++ks) {
        const int k0 = ks * 32;
        // ---- issue next-step W DMA into the other buffer ----
        if (ks < 15) STAGE_W(k0 + 32, cur ^ 1);

        // ---- convert held A-raw(k0) -> 3 LDS planes. Compiler auto-waits
        //      vmcnt(6): A(k0)+W(k0) done, W(k0+32) stays in flight. ----
#pragma unroll
        for (int i = 0; i < 2; ++i) {
            float vv[8] = {dR[i][0].x*mR[i][0].x, dR[i][0].y*mR[i][0].y,
                           dR[i][0].z*mR[i][0].z, dR[i][0].w*mR[i][0].w,
                           dR[i][1].x*mR[i][1].x, dR[i][1].y*mR[i][1].y,
                           dR[i][1].z*mR[i][1].z, dR[i][1].w*mR[i][1].w};
            uint32 q0[4], q1[4], q2[4];
#pragma unroll
            for (int pr = 0; pr < 4; ++pr) {
                const float a = vv[2*pr], b = vv[2*pr+1];
                q0[pr] = pkbf16(a, b);
                const float ra = a - __uint_as_float(q0[pr] << 16);
                const float rb = b - __uint_as_float(q0[pr] & 0xFFFF0000u);
                q1[pr] = pkbf16(ra, rb);
                const float sa = ra - __uint_as_float(q1[pr] << 16);
                const float sb = rb - __uint_as_float(q1[pr] & 0xFFFF0000u);
                q2[pr] = pkbf16(sa, sb);
            }
            uint4 pk;
            pk.x = q0[0]; pk.y = q0[1]; pk.z = q0[2]; pk.w = q0[3];
            *(uint4*)(&As3[dstA[i]]) = pk;
            pk.x = q1[0]; pk.y = q1[1]; pk.z = q1[2]; pk.w = q1[3];
            *(uint4*)(&As3[SPL + dstA[i]]) = pk;
            pk.x = q2[0]; pk.y = q2[1]; pk.z = q2[2]; pk.w = q2[3];
            *(uint4*)(&As3[2*SPL + dstA[i]]) = pk;
        }

        // ---- issue next-step A-raw loads (regs free after convert) ----
        if (ks < 15) {
            const int kn = k0 + 32;
#pragma unroll
            for (int i = 0; i < 2; ++i) {
                dR[i][0] = *(const float4*)(dsrc[i] + kn);
                dR[i][1] = *(const float4*)(dsrc[i] + kn + 4);
                mR[i][0] = *(const float4*)(msrc[i] + kn);
                mR[i][1] = *(const float4*)(msrc[i] + kn + 4);
            }
        }

        // ---- bar1: ds_writes visible; vmem stays in flight ----
        asm volatile("s_waitcnt lgkmcnt(0)" ::: "memory");
        asm volatile("s_barrier" ::: "memory");

        const int qa = q ^ ((r16 >> 1) & 3);             // read-side swizzle
        bf16x8 af[4][3], bfr[4][3];
#pragma unroll
        for (int mt = 0; mt < 4; ++mt)
#pragma unroll
            for (int s = 0; s < 3; ++s)
                af[mt][s] = *(const bf16x8*)(&As3[s*SPL + (wm*64 + mt*16 + r16)*SPW + qa*8]);
#pragma unroll
        for (int nt = 0; nt < 4; ++nt)
#pragma unroll
            for (int s = 0; s < 3; ++s)
                bfr[nt][s] = *(const bf16x8*)(&Ws3[cur][s*SPL + (wn*64 + nt*16 + r16)*SPW + qa*8]);

        __builtin_amdgcn_s_setprio(1);
#define PRODUCT(SA, SB)                                                          \
        {                                                                        \
            _Pragma("unroll")                                                    \
            for (int mt = 0; mt < 4; ++mt) {                                     \
                _Pragma("unroll")                                                \
                for (int nt = 0; nt < 4; ++nt)                                   \
                    acc[mt][nt] = __builtin_amdgcn_mfma_f32_16x16x32_bf16(       \
                        af[mt][SA], bfr[nt][SB], acc[mt][nt], 0, 0, 0);          \
            }                                                                    \
        }
        PRODUCT(0, 0)
        PRODUCT(0, 1)
        PRODUCT(1, 0)
        PRODUCT(1, 1)
        PRODUCT(0, 2)
        PRODUCT(2, 0)
#undef PRODUCT
        __builtin_amdgcn_s_setprio(0);

        // ---- bar2: protect As3 (next convert) & frag reads ----
        asm volatile("s_barrier" ::: "memory");
        cur ^= 1;
    }
#undef STAGE_W

    // ---- epilogue: +b1, write hbuf, fp64 per-block BN partials ----
    float b1c[4];
#pragma unroll
    for (int nt = 0; nt < 4; ++nt) b1c[nt] = b1[d0 + wn*64 + nt*16 + r16];

    double sd[4], sq[4];
#pragma unroll
    for (int nt = 0; nt < 4; ++nt) { sd[nt] = 0.0; sq[nt] = 0.0; }

#pragma unroll
    for (int mt = 0; mt < 4; ++mt)
#pragma unroll
        for (int r = 0; r < 4; ++r) {
            const int row = R + wm*64 + mt*16 + q*4 + r;
            float* op = hbuf + (size_t)row * D_ + d0 + wn*64 + r16;
#pragma unroll
            for (int nt = 0; nt < 4; ++nt) {
                const float hf = acc[mt][nt][r] + b1c[nt];
                op[nt*16] = hf;
                const double dh = (double)hf;
                sd[nt] += dh;
                sq[nt] = fma(dh, dh, sq[nt]);
            }
        }
#pragma unroll
    for (int nt = 0; nt < 4; ++nt) {
        sd[nt] += __shfl_xor(sd[nt], 16); sd[nt] += __shfl_xor(sd[nt], 32);
        sq[nt] += __shfl_xor(sq[nt], 16); sq[nt] += __shfl_xor(sq[nt], 32);
    }
    double* dsh = (double*)&As3[0];
    __syncthreads();
    if (q == 0) {
#pragma unroll
        for (int nt = 0; nt < 4; ++nt) {
            dsh[(w*64 + nt*16 + r16)*2 + 0] = sd[nt];
            dsh[(w*64 + nt*16 + r16)*2 + 1] = sq[nt];
        }
    }
    __syncthreads();
    if (tid < 128) {
        const int col = tid;
        const int gg = col >> 6, c = col & 63;
        const double S = dsh[((2*gg)*64 + c)*2 + 0] + dsh[((2*gg+1)*64 + c)*2 + 0];
        const double Q = dsh[((2*gg)*64 + c)*2 + 1] + dsh[((2*gg+1)*64 + c)*2 + 1];
        const int bt = b_base >> 7;
        pSum[((size_t)(bt*Tc + tc))*D_ + d0 + col] = S;
        pSq [((size_t)(bt*Tc + tc))*D_ + d0 + col] = Q;
    }
}

// ---------------- finalize ----------------
__global__ __launch_bounds__(256)
void finalize_kernel(const double* __restrict__ pSum, const double* __restrict__ pSq,
                     const float* __restrict__ gamma, const float* __restrict__ bn_beta,
                     float* __restrict__ scaleArr, float* __restrict__ shiftArr, int Tc)
{
    const int tc = blockIdx.x;
    const int d = blockIdx.y * 256 + threadIdx.x;
    double S = 0.0, Q = 0.0;
#pragma unroll
    for (int bt = 0; bt < 4; ++bt) {
        S += pSum[((size_t)(bt * Tc + tc)) * D_ + d];
        Q += pSq [((size_t)(bt * Tc + tc)) * D_ + d];
    }
    const double mean = S / (double)B_;
    const double var  = Q / (double)B_ - mean * mean;
    const double rs   = 1.0 / sqrt(var + 1e-5);
    const double gm   = (double)gamma[d] * rs;
    scaleArr[tc * D_ + d] = (float)gm;
    shiftArr[tc * D_ + d] = (float)((double)bn_beta[d] - gm * mean);
}

// ---------------- scanA: 4-deep prefetch; spikes -> 64-bit ballot mask ----------------
__global__ __launch_bounds__(256)
void scanA_kernel(const float* __restrict__ hbuf, const float* __restrict__ scaleArr,
                  const float* __restrict__ shiftArr, uint64* __restrict__ spkM,
                  float* __restrict__ sMem1, float* __restrict__ sSpk1, int t0, int Tc)
{
    const int e = blockIdx.x * 256 + threadIdx.x;   // b*512 + d
    const int d = e & 511;
    const int lane = threadIdx.x & 63;
    const int mword = (e >> 6);                     // global 64-d group = b*8 + (d>>6)

    float m1, s1;
    if (t0 == 0) { m1 = 0.f; s1 = 0.f; }
    else { m1 = sMem1[e]; s1 = sSpk1[e]; }

    float hv[4], sc[4], sf[4];
#pragma unroll
    for (int j = 0; j < 4; ++j) {
        const int tcj = (j < Tc) ? j : (Tc - 1);
        hv[j] = hbuf[(size_t)tcj * (B_ * D_) + e];
        sc[j] = scaleArr[tcj * D_ + d];
        sf[j] = shiftArr[tcj * D_ + d];
    }

    for (int tc = 0; tc < Tc; tc += 4) {
        float hvN[4], scN[4], sfN[4];
#pragma unroll
        for (int j = 0; j < 4; ++j) {
            int tn = tc + 4 + j; tn = (tn < Tc) ? tn : (Tc - 1);
            hvN[j] = hbuf[(size_t)tn * (B_ * D_) + e];
            scN[j] = scaleArr[tn * D_ + d];
            sfN[j] = shiftArr[tn * D_ + d];
        }
#pragma unroll
        for (int j = 0; j < 4; ++j) {
            if (tc + j < Tc) {
                const float cur1 = fmaf(sc[j], hv[j], sf[j]);
                m1 = fmaf(0.5f, m1, cur1) - s1;
                s1 = ((m1 - 1.0f) > 0.f) ? 1.f : 0.f;
                const uint64 mask = __ballot(s1 == 1.f);
                if (lane == 0)
                    spkM[(size_t)(tc + j) * (B_ * 8) + mword] = mask;
            }
        }
#pragma unroll
        for (int j = 0; j < 4; ++j) { hv[j] = hvN[j]; sc[j] = scN[j]; sf[j] = sfN[j]; }
    }

    sMem1[e] = m1;
    sSpk1[e] = s1;
}

// ---------------- gemm2: 8 threads/row, bitwise-identical reduction tree ----------
__global__ __launch_bounds__(256)
void gemm2_kernel(const uint64* __restrict__ spkM, const float* __restrict__ W2,
                  const float* __restrict__ b2, float* __restrict__ cur2)
{
    const int g = blockIdx.x * 256 + threadIdx.x;
    const int row = g >> 3;                          // t*B + b
    const int i = g & 7;
    const unsigned char* sp = (const unsigned char*)spkM;

    float P[8][O_];
#pragma unroll
    for (int c = 0; c < 8; ++c) {
        const uint32 byte = sp[(size_t)row * 64 + c * 8 + i];
        float f[8];
#pragma unroll
        for (int j = 0; j < 8; ++j)
            f[j] = (byte & (1u << j)) ? 1.0f : 0.0f;
#pragma unroll
        for (int o = 0; o < O_; ++o) {
            const float* wp = W2 + o * D_ + (i + 8 * c) * 8;
            const float4 wa = *(const float4*)(wp);
            const float4 wb = *(const float4*)(wp + 4);
            float v = f[0] * wa.x;
            v = fmaf(f[1], wa.y, v); v = fmaf(f[2], wa.z, v); v = fmaf(f[3], wa.w, v);
            v = fmaf(f[4], wb.x, v); v = fmaf(f[5], wb.y, v); v = fmaf(f[6], wb.z, v);
            v = fmaf(f[7], wb.w, v);
            P[c][o] = v;
        }
    }

    float p[O_];
#pragma unroll
    for (int o = 0; o < O_; ++o) {
        const float a1 = P[0][o] + P[4][o];
        const float a2 = P[2][o] + P[6][o];
        const float a3 = P[1][o] + P[5][o];
        const float a4 = P[3][o] + P[7][o];
        p[o] = (a1 + a2) + (a3 + a4);
    }
#pragma unroll
    for (int o = 0; o < O_; ++o) {
        p[o] += __shfl_xor(p[o], 4);
        p[o] += __shfl_xor(p[o], 2);
        p[o] += __shfl_xor(p[o], 1);
    }

    float out0 = 0.f, out1 = 0.f;
#pragma unroll
    for (int o = 0; o < 8; ++o)
        if (i == o) out0 = p[o] + b2[o];
    if (i == 0) out1 = p[8] + b2[8];
    if (i == 1) out1 = p[9] + b2[9];
    cur2[(size_t)row * O_ + i] = out0;
    if (i < 2)
        cur2[(size_t)row * O_ + 8 + i] = out1;
}

// ---------------- scanB ----------------
__global__ __launch_bounds__(256)
void scanB_kernel(const float* __restrict__ cur2, float* __restrict__ out,
                  float* __restrict__ sMem2, float* __restrict__ sSpk2, int t0, int Tc)
{
    const int idx = blockIdx.x * 256 + threadIdx.x;
    float mem2, spk2;
    if (t0 == 0) { mem2 = 0.f; spk2 = 0.f; }
    else { mem2 = sMem2[idx]; spk2 = sSpk2[idx]; }

    float v[4], vn[4];
#pragma unroll
    for (int j = 0; j < 4; ++j) v[j] = cur2[(size_t)j * (B_ * O_) + idx];

    for (int tg = 0; tg < Tc; tg += 4) {
        if (tg + 4 < Tc) {
#pragma unroll
            for (int j = 0; j < 4; ++j)
                vn[j] = cur2[(size_t)(tg + 4 + j) * (B_ * O_) + idx];
        }
#pragma unroll
        for (int j = 0; j < 4; ++j) {
            mem2 = fmaf(0.5f, mem2, v[j]) - spk2;
            spk2 = ((mem2 - 1.0f) > 0.f) ? 1.f : 0.f;
            out[(size_t)(t0 + tg + j) * (B_ * O_) + idx] = spk2;
        }
#pragma unroll
        for (int j = 0; j < 4; ++j) v[j] = vn[j];
    }
    sMem2[idx] = mem2;
    sSpk2[idx] = spk2;
}

extern "C" void kernel_launch(void* const* d_in, const int* in_sizes, int n_in,
                              void* d_out, int out_size, void* d_ws, size_t ws_size,
                              hipStream_t stream) {
    const float* data    = (const float*)d_in[0];
    const float* drop    = (const float*)d_in[1];
    const float* W1      = (const float*)d_in[2];
    const float* b1      = (const float*)d_in[3];
    const float* gamma   = (const float*)d_in[4];
    const float* bn_beta = (const float*)d_in[5];
    const float* W2      = (const float*)d_in[6];
    const float* b2      = (const float*)d_in[7];
    float* out = (float*)d_out;

    const size_t fixedBytes = 1572864 + 2*1048576 + 2*20480;
    // per-t: hbuf 1MB + spkM 32KB + cur2 20KB + scale/shift 4KB + pSum/pSq 32KB
    const size_t perT = 1048576 + 32768 + 20480 + 4096 + 32768;
    int Tc = T_;
    while (Tc > 2 && fixedBytes + (size_t)Tc * perT > ws_size) Tc >>= 1;

    char* p = (char*)d_ws;
    double* pSum    = (double*)p; p += (size_t)4 * Tc * D_ * 8;
    double* pSq     = (double*)p; p += (size_t)4 * Tc * D_ * 8;
    float* hbuf     = (float*)p; p += (size_t)Tc * B_ * D_ * 4;
    float* scaleArr = (float*)p; p += (size_t)Tc * D_ * 4;
    float* shiftArr = (float*)p; p += (size_t)Tc * D_ * 4;
    float* sMem1    = (float*)p; p += (size_t)B_ * D_ * 4;
    float* sSpk1    = (float*)p; p += (size_t)B_ * D_ * 4;
    float* sMem2    = (float*)p; p += (size_t)B_ * O_ * 4;
    float* sSpk2    = (float*)p; p += (size_t)B_ * O_ * 4;
    float* cur2     = (float*)p; p += (size_t)Tc * B_ * O_ * 4;
    unsigned short* Wsp = (unsigned short*)p; p += (size_t)3 * D_ * D_ * 2;
    uint64* spkM    = (uint64*)p; p += (size_t)Tc * B_ * 8 * 8;

    presplitW_kernel<<<256, 256, 0, stream>>>(W1, Wsp);

    for (int t0 = 0; t0 < T_; t0 += Tc) {
        gemm1_kernel<<<Tc * 16, 256, 0, stream>>>(data, drop, Wsp, b1, hbuf,
                                                  pSum, pSq, t0, Tc);
        finalize_kernel<<<dim3(Tc, D_ / 256), 256, 0, stream>>>(
            pSum, pSq, gamma, bn_beta, scaleArr, shiftArr, Tc);
        scanA_kernel<<<(B_ * D_) / 256, 256, 0, stream>>>(hbuf, scaleArr, shiftArr, spkM,
                                                          sMem1, sSpk1, t0, Tc);
        gemm2_kernel<<<Tc * 16, 256, 0, stream>>>(spkM, W2, b2, cur2);
        scanB_kernel<<<20, 256, 0, stream>>>(cur2, out, sMem2, sSpk2, t0, Tc);
    }
}

// Round 7
// 506.605 us; speedup vs baseline: 1.0258x; 1.0258x over previous
//
#include <hip/hip_runtime.h>
#include <math.h>

#define B_ 512
#define T_ 128
#define D_ 512
#define O_ 10

typedef unsigned int uint32;
typedef unsigned long long uint64;
typedef short bf16x8 __attribute__((ext_vector_type(8)));   // 8 bf16 = 4 VGPRs
typedef float f32x4 __attribute__((ext_vector_type(4)));

__device__ __forceinline__ uint32 bf16rne(float f) {
    uint32 u = __float_as_uint(f);
    return (u + 0x7FFFu + ((u >> 16) & 1u)) >> 16;
}
__device__ __forceinline__ float bf16f(uint32 h) { return __uint_as_float(h << 16); }

// packed RNE pair: low16 = bf16(lo), high16 = bf16(hi)
__device__ __forceinline__ uint32 pkbf16(float lo, float hi) {
    return bf16rne(lo) | (bf16rne(hi) << 16);
}

__device__ __forceinline__ void gload16_lds(const void* g, void* l) {
    __builtin_amdgcn_global_load_lds(
        (const __attribute__((address_space(1))) unsigned int*)g,
        (__attribute__((address_space(3))) unsigned int*)l, 16, 0, 0);
}

// ---------------- pre-split W1 into 3 bf16 planes [3][512][512] ----------------
__global__ __launch_bounds__(256)
void presplitW_kernel(const float* __restrict__ W1, unsigned short* __restrict__ Wsp)
{
    const int idx = blockIdx.x * 256 + threadIdx.x;
    const float4 v = *(const float4*)(W1 + (size_t)idx * 4);
    float vv[4] = {v.x, v.y, v.z, v.w};
    uint32 c0[4], c1[4], c2[4];
#pragma unroll
    for (int i = 0; i < 4; ++i) {
        c0[i] = bf16rne(vv[i]);
        float r = vv[i] - bf16f(c0[i]);
        c1[i] = bf16rne(r);
        float r2 = r - bf16f(c1[i]);
        c2[i] = bf16rne(r2);
    }
    const size_t base = (size_t)idx * 4;
    uint2 w;
    w.x = c0[0] | (c0[1] << 16); w.y = c0[2] | (c0[3] << 16);
    *(uint2*)(Wsp + base) = w;
    w.x = c1[0] | (c1[1] << 16); w.y = c1[2] | (c1[3] << 16);
    *(uint2*)(Wsp + 262144 + base) = w;
    w.x = c2[0] | (c2[1] << 16); w.y = c2[2] | (c2[3] << 16);
    *(uint2*)(Wsp + 524288 + base) = w;
}

// ---------------- GEMM1: bf16x3-split MFMA + fused fp64 BN partials ----------------
// R7: R6's counted-vmcnt pipeline with CORRECT barrier implementation.
// R6 artifact: asm("s_barrier":::"memory") forces the compiler to insert
// s_waitcnt vmcnt(0) lgkmcnt(0) before the asm (opaque memory clobber) ->
// drain-everything, identical to __syncthreads -> identical profile.
// Fix (m194-m201 template): __builtin_amdgcn_s_barrier() (no implied drain)
// + clobber-free s_waitcnt asm + sched_barrier(0) pins (rule #18).
// Steady state across bar1: W(k+1) 6 DMAs + A(k+1) 8 loads stay in flight
// under the 96-MFMA block; W(k) is drained by the compiler's automatic
// vmcnt(6) when the convert reads the A(k) regs (W(k) older than A(k)).
#define SPW 32
#define SPL (128*SPW)

__global__ __launch_bounds__(256)
void gemm1_kernel(const float* __restrict__ data, const float* __restrict__ drop,
                  const unsigned short* __restrict__ Wsp, const float* __restrict__ b1,
                  float* __restrict__ hbuf, double* __restrict__ pSum,
                  double* __restrict__ pSq, int t0, int Tc)
{
    __shared__ __align__(16) unsigned short As3[3 * SPL];        // 24 KB
    __shared__ __align__(16) unsigned short Ws3[2][3 * SPL];     // 48 KB

    const int tid = threadIdx.x;
    const int bid = blockIdx.x;
    // XCD swizzle (verified: FETCH 606->159MB)
    const int xcd = bid & 7;
    const int rest = bid >> 3;
    const int yy = rest & 3;
    const int g = (rest >> 2) * 8 + xcd;

    const int R = g * 128;
    const int tc = R >> 9;
    const int b_base = R & 511;
    const int t = t0 + tc;
    const int d0 = yy * 128;

    const int w = tid >> 6;
    const int lane = tid & 63;
    const int wm = w & 1, wn = w >> 1;
    const int q = lane >> 4, r16 = lane & 15;

    f32x4 acc[4][4];
#pragma unroll
    for (int i = 0; i < 4; ++i)
#pragma unroll
        for (int j = 0; j < 4; ++j) acc[i][j] = (f32x4){0.f, 0.f, 0.f, 0.f};

    // ---- per-thread constant staging geometry ----
    int dstA[2];
    const float* dsrc[2];
    const float* msrc[2];
#pragma unroll
    for (int i = 0; i < 2; ++i) {
        const int p = tid + i * 256;
        const int m = p >> 2;
        const int qg = p & 3;
        dstA[i] = m * SPW + (qg ^ ((m >> 1) & 3)) * 8;
        dsrc[i] = data + ((size_t)(b_base + m) * T_ + t) * D_ + qg * 8;
        msrc[i] = drop + ((size_t)t * B_ + b_base + m) * D_ + qg * 8;
    }

#define STAGE_W(K0, BUF)                                                        \
    {                                                                           \
        _Pragma("unroll")                                                       \
        for (int i_ = 0; i_ < 6; ++i_) {                                        \
            const int p_ = tid + i_ * 256;                                      \
            const int s_ = p_ >> 9;                                             \
            const int rem_ = p_ & 511;                                          \
            const int n_ = rem_ >> 2;                                           \
            const int qs_ = rem_ & 3;                                           \
            const int qg_ = qs_ ^ ((n_ >> 1) & 3);                              \
            gload16_lds(Wsp + (size_t)s_ * 262144 + (size_t)(d0 + n_) * 512     \
                            + (K0) + qg_ * 8,                                   \
                        &Ws3[BUF][(size_t)p_ * 8]);                             \
        }                                                                       \
    }

    // ---- prologue: W(0) DMA FIRST (must be older than A(0) loads) ----
    STAGE_W(0, 0);
    float4 dR[2][2], mR[2][2];
#pragma unroll
    for (int i = 0; i < 2; ++i) {
        dR[i][0] = *(const float4*)(dsrc[i]);
        dR[i][1] = *(const float4*)(dsrc[i] + 4);
        mR[i][0] = *(const float4*)(msrc[i]);
        mR[i][1] = *(const float4*)(msrc[i] + 4);
    }

    int cur = 0;
    for (int ks = 0; ks < 16; ++ks) {
        const int k0 = ks * 32;
        // ---- issue next-step W DMA into the other buffer ----
        if (ks < 15) STAGE_W(k0 + 32, cur ^ 1);

        // ---- convert held A-raw(k0) -> 3 LDS planes. Compiler auto-waits
        //      vmcnt(6): A(k0)+W(k0) done, W(k0+32) stays in flight. ----
#pragma unroll
        for (int i = 0; i < 2; ++i) {
            float vv[8] = {dR[i][0].x*mR[i][0].x, dR[i][0].y*mR[i][0].y,
                           dR[i][0].z*mR[i][0].z, dR[i][0].w*mR[i][0].w,
                           dR[i][1].x*mR[i][1].x, dR[i][1].y*mR[i][1].y,
                           dR[i][1].z*mR[i][1].z, dR[i][1].w*mR[i][1].w};
            uint32 q0[4], q1[4], q2[4];
#pragma unroll
            for (int pr = 0; pr < 4; ++pr) {
                const float a = vv[2*pr], b = vv[2*pr+1];
                q0[pr] = pkbf16(a, b);
                const float ra = a - __uint_as_float(q0[pr] << 16);
                const float rb = b - __uint_as_float(q0[pr] & 0xFFFF0000u);
                q1[pr] = pkbf16(ra, rb);
                const float sa = ra - __uint_as_float(q1[pr] << 16);
                const float sb = rb - __uint_as_float(q1[pr] & 0xFFFF0000u);
                q2[pr] = pkbf16(sa, sb);
            }
            uint4 pk;
            pk.x = q0[0]; pk.y = q0[1]; pk.z = q0[2]; pk.w = q0[3];
            *(uint4*)(&As3[dstA[i]]) = pk;
            pk.x = q1[0]; pk.y = q1[1]; pk.z = q1[2]; pk.w = q1[3];
            *(uint4*)(&As3[SPL + dstA[i]]) = pk;
            pk.x = q2[0]; pk.y = q2[1]; pk.z = q2[2]; pk.w = q2[3];
            *(uint4*)(&As3[2*SPL + dstA[i]]) = pk;
        }

        // ---- issue next-step A-raw loads (regs free after convert) ----
        if (ks < 15) {
            const int kn = k0 + 32;
#pragma unroll
            for (int i = 0; i < 2; ++i) {
                dR[i][0] = *(const float4*)(dsrc[i] + kn);
                dR[i][1] = *(const float4*)(dsrc[i] + kn + 4);
                mR[i][0] = *(const float4*)(msrc[i] + kn);
                mR[i][1] = *(const float4*)(msrc[i] + kn + 4);
            }
        }

        // ---- bar1: As3 ds_writes visible; vmem (W(k+1)+A(k+1)) stays in flight ----
        __builtin_amdgcn_sched_barrier(0);
        asm volatile("s_waitcnt lgkmcnt(0)");
        __builtin_amdgcn_s_barrier();
        __builtin_amdgcn_sched_barrier(0);

        const int qa = q ^ ((r16 >> 1) & 3);             // read-side swizzle
        bf16x8 af[4][3], bfr[4][3];
#pragma unroll
        for (int mt = 0; mt < 4; ++mt)
#pragma unroll
            for (int s = 0; s < 3; ++s)
                af[mt][s] = *(const bf16x8*)(&As3[s*SPL + (wm*64 + mt*16 + r16)*SPW + qa*8]);
#pragma unroll
        for (int nt = 0; nt < 4; ++nt)
#pragma unroll
            for (int s = 0; s < 3; ++s)
                bfr[nt][s] = *(const bf16x8*)(&Ws3[cur][s*SPL + (wn*64 + nt*16 + r16)*SPW + qa*8]);

        __builtin_amdgcn_s_setprio(1);
#define PRODUCT(SA, SB)                                                          \
        {                                                                        \
            _Pragma("unroll")                                                    \
            for (int mt = 0; mt < 4; ++mt) {                                     \
                _Pragma("unroll")                                                \
                for (int nt = 0; nt < 4; ++nt)                                   \
                    acc[mt][nt] = __builtin_amdgcn_mfma_f32_16x16x32_bf16(       \
                        af[mt][SA], bfr[nt][SB], acc[mt][nt], 0, 0, 0);          \
            }                                                                    \
        }
        PRODUCT(0, 0)
        PRODUCT(0, 1)
        PRODUCT(1, 0)
        PRODUCT(1, 1)
        PRODUCT(0, 2)
        PRODUCT(2, 0)
#undef PRODUCT
        __builtin_amdgcn_s_setprio(0);

        // ---- bar2: frag ds_reads retired (compiler-waited before MFMA issue);
        //      protects As3/Ws3[cur] from next step's writes. No vmem drain. ----
        __builtin_amdgcn_sched_barrier(0);
        __builtin_amdgcn_s_barrier();
        __builtin_amdgcn_sched_barrier(0);
        cur ^= 1;
    }
#undef STAGE_W

    // ---- epilogue: +b1, write hbuf, fp64 per-block BN partials ----
    float b1c[4];
#pragma unroll
    for (int nt = 0; nt < 4; ++nt) b1c[nt] = b1[d0 + wn*64 + nt*16 + r16];

    double sd[4], sq[4];
#pragma unroll
    for (int nt = 0; nt < 4; ++nt) { sd[nt] = 0.0; sq[nt] = 0.0; }

#pragma unroll
    for (int mt = 0; mt < 4; ++mt)
#pragma unroll
        for (int r = 0; r < 4; ++r) {
            const int row = R + wm*64 + mt*16 + q*4 + r;
            float* op = hbuf + (size_t)row * D_ + d0 + wn*64 + r16;
#pragma unroll
            for (int nt = 0; nt < 4; ++nt) {
                const float hf = acc[mt][nt][r] + b1c[nt];
                op[nt*16] = hf;
                const double dh = (double)hf;
                sd[nt] += dh;
                sq[nt] = fma(dh, dh, sq[nt]);
            }
        }
#pragma unroll
    for (int nt = 0; nt < 4; ++nt) {
        sd[nt] += __shfl_xor(sd[nt], 16); sd[nt] += __shfl_xor(sd[nt], 32);
        sq[nt] += __shfl_xor(sq[nt], 16); sq[nt] += __shfl_xor(sq[nt], 32);
    }
    double* dsh = (double*)&As3[0];
    __syncthreads();
    if (q == 0) {
#pragma unroll
        for (int nt = 0; nt < 4; ++nt) {
            dsh[(w*64 + nt*16 + r16)*2 + 0] = sd[nt];
            dsh[(w*64 + nt*16 + r16)*2 + 1] = sq[nt];
        }
    }
    __syncthreads();
    if (tid < 128) {
        const int col = tid;
        const int gg = col >> 6, c = col & 63;
        const double S = dsh[((2*gg)*64 + c)*2 + 0] + dsh[((2*gg+1)*64 + c)*2 + 0];
        const double Q = dsh[((2*gg)*64 + c)*2 + 1] + dsh[((2*gg+1)*64 + c)*2 + 1];
        const int bt = b_base >> 7;
        pSum[((size_t)(bt*Tc + tc))*D_ + d0 + col] = S;
        pSq [((size_t)(bt*Tc + tc))*D_ + d0 + col] = Q;
    }
}

// ---------------- finalize ----------------
__global__ __launch_bounds__(256)
void finalize_kernel(const double* __restrict__ pSum, const double* __restrict__ pSq,
                     const float* __restrict__ gamma, const float* __restrict__ bn_beta,
                     float* __restrict__ scaleArr, float* __restrict__ shiftArr, int Tc)
{
    const int tc = blockIdx.x;
    const int d = blockIdx.y * 256 + threadIdx.x;
    double S = 0.0, Q = 0.0;
#pragma unroll
    for (int bt = 0; bt < 4; ++bt) {
        S += pSum[((size_t)(bt * Tc + tc)) * D_ + d];
        Q += pSq [((size_t)(bt * Tc + tc)) * D_ + d];
    }
    const double mean = S / (double)B_;
    const double var  = Q / (double)B_ - mean * mean;
    const double rs   = 1.0 / sqrt(var + 1e-5);
    const double gm   = (double)gamma[d] * rs;
    scaleArr[tc * D_ + d] = (float)gm;
    shiftArr[tc * D_ + d] = (float)((double)bn_beta[d] - gm * mean);
}

// ---------------- scanA: 4-deep prefetch; spikes -> 64-bit ballot mask ----------------
__global__ __launch_bounds__(256)
void scanA_kernel(const float* __restrict__ hbuf, const float* __restrict__ scaleArr,
                  const float* __restrict__ shiftArr, uint64* __restrict__ spkM,
                  float* __restrict__ sMem1, float* __restrict__ sSpk1, int t0, int Tc)
{
    const int e = blockIdx.x * 256 + threadIdx.x;   // b*512 + d
    const int d = e & 511;
    const int lane = threadIdx.x & 63;
    const int mword = (e >> 6);                     // global 64-d group = b*8 + (d>>6)

    float m1, s1;
    if (t0 == 0) { m1 = 0.f; s1 = 0.f; }
    else { m1 = sMem1[e]; s1 = sSpk1[e]; }

    float hv[4], sc[4], sf[4];
#pragma unroll
    for (int j = 0; j < 4; ++j) {
        const int tcj = (j < Tc) ? j : (Tc - 1);
        hv[j] = hbuf[(size_t)tcj * (B_ * D_) + e];
        sc[j] = scaleArr[tcj * D_ + d];
        sf[j] = shiftArr[tcj * D_ + d];
    }

    for (int tc = 0; tc < Tc; tc += 4) {
        float hvN[4], scN[4], sfN[4];
#pragma unroll
        for (int j = 0; j < 4; ++j) {
            int tn = tc + 4 + j; tn = (tn < Tc) ? tn : (Tc - 1);
            hvN[j] = hbuf[(size_t)tn * (B_ * D_) + e];
            scN[j] = scaleArr[tn * D_ + d];
            sfN[j] = shiftArr[tn * D_ + d];
        }
#pragma unroll
        for (int j = 0; j < 4; ++j) {
            if (tc + j < Tc) {
                const float cur1 = fmaf(sc[j], hv[j], sf[j]);
                m1 = fmaf(0.5f, m1, cur1) - s1;
                s1 = ((m1 - 1.0f) > 0.f) ? 1.f : 0.f;
                const uint64 mask = __ballot(s1 == 1.f);
                if (lane == 0)
                    spkM[(size_t)(tc + j) * (B_ * 8) + mword] = mask;
            }
        }
#pragma unroll
        for (int j = 0; j < 4; ++j) { hv[j] = hvN[j]; sc[j] = scN[j]; sf[j] = sfN[j]; }
    }

    sMem1[e] = m1;
    sSpk1[e] = s1;
}

// ---------------- gemm2: 8 threads/row, bitwise-identical reduction tree ----------
__global__ __launch_bounds__(256)
void gemm2_kernel(const uint64* __restrict__ spkM, const float* __restrict__ W2,
                  const float* __restrict__ b2, float* __restrict__ cur2)
{
    const int g = blockIdx.x * 256 + threadIdx.x;
    const int row = g >> 3;                          // t*B + b
    const int i = g & 7;
    const unsigned char* sp = (const unsigned char*)spkM;

    float P[8][O_];
#pragma unroll
    for (int c = 0; c < 8; ++c) {
        const uint32 byte = sp[(size_t)row * 64 + c * 8 + i];
        float f[8];
#pragma unroll
        for (int j = 0; j < 8; ++j)
            f[j] = (byte & (1u << j)) ? 1.0f : 0.0f;
#pragma unroll
        for (int o = 0; o < O_; ++o) {
            const float* wp = W2 + o * D_ + (i + 8 * c) * 8;
            const float4 wa = *(const float4*)(wp);
            const float4 wb = *(const float4*)(wp + 4);
            float v = f[0] * wa.x;
            v = fmaf(f[1], wa.y, v); v = fmaf(f[2], wa.z, v); v = fmaf(f[3], wa.w, v);
            v = fmaf(f[4], wb.x, v); v = fmaf(f[5], wb.y, v); v = fmaf(f[6], wb.z, v);
            v = fmaf(f[7], wb.w, v);
            P[c][o] = v;
        }
    }

    float p[O_];
#pragma unroll
    for (int o = 0; o < O_; ++o) {
        const float a1 = P[0][o] + P[4][o];
        const float a2 = P[2][o] + P[6][o];
        const float a3 = P[1][o] + P[5][o];
        const float a4 = P[3][o] + P[7][o];
        p[o] = (a1 + a2) + (a3 + a4);
    }
#pragma unroll
    for (int o = 0; o < O_; ++o) {
        p[o] += __shfl_xor(p[o], 4);
        p[o] += __shfl_xor(p[o], 2);
        p[o] += __shfl_xor(p[o], 1);
    }

    float out0 = 0.f, out1 = 0.f;
#pragma unroll
    for (int o = 0; o < 8; ++o)
        if (i == o) out0 = p[o] + b2[o];
    if (i == 0) out1 = p[8] + b2[8];
    if (i == 1) out1 = p[9] + b2[9];
    cur2[(size_t)row * O_ + i] = out0;
    if (i < 2)
        cur2[(size_t)row * O_ + 8 + i] = out1;
}

// ---------------- scanB ----------------
__global__ __launch_bounds__(256)
void scanB_kernel(const float* __restrict__ cur2, float* __restrict__ out,
                  float* __restrict__ sMem2, float* __restrict__ sSpk2, int t0, int Tc)
{
    const int idx = blockIdx.x * 256 + threadIdx.x;
    float mem2, spk2;
    if (t0 == 0) { mem2 = 0.f; spk2 = 0.f; }
    else { mem2 = sMem2[idx]; spk2 = sSpk2[idx]; }

    float v[4], vn[4];
#pragma unroll
    for (int j = 0; j < 4; ++j) v[j] = cur2[(size_t)j * (B_ * O_) + idx];

    for (int tg = 0; tg < Tc; tg += 4) {
        if (tg + 4 < Tc) {
#pragma unroll
            for (int j = 0; j < 4; ++j)
                vn[j] = cur2[(size_t)(tg + 4 + j) * (B_ * O_) + idx];
        }
#pragma unroll
        for (int j = 0; j < 4; ++j) {
            mem2 = fmaf(0.5f, mem2, v[j]) - spk2;
            spk2 = ((mem2 - 1.0f) > 0.f) ? 1.f : 0.f;
            out[(size_t)(t0 + tg + j) * (B_ * O_) + idx] = spk2;
        }
#pragma unroll
        for (int j = 0; j < 4; ++j) v[j] = vn[j];
    }
    sMem2[idx] = mem2;
    sSpk2[idx] = spk2;
}

extern "C" void kernel_launch(void* const* d_in, const int* in_sizes, int n_in,
                              void* d_out, int out_size, void* d_ws, size_t ws_size,
                              hipStream_t stream) {
    const float* data    = (const float*)d_in[0];
    const float* drop    = (const float*)d_in[1];
    const float* W1      = (const float*)d_in[2];
    const float* b1      = (const float*)d_in[3];
    const float* gamma   = (const float*)d_in[4];
    const float* bn_beta = (const float*)d_in[5];
    const float* W2      = (const float*)d_in[6];
    const float* b2      = (const float*)d_in[7];
    float* out = (float*)d_out;

    const size_t fixedBytes = 1572864 + 2*1048576 + 2*20480;
    // per-t: hbuf 1MB + spkM 32KB + cur2 20KB + scale/shift 4KB + pSum/pSq 32KB
    const size_t perT = 1048576 + 32768 + 20480 + 4096 + 32768;
    int Tc = T_;
    while (Tc > 2 && fixedBytes + (size_t)Tc * perT > ws_size) Tc >>= 1;

    char* p = (char*)d_ws;
    double* pSum    = (double*)p; p += (size_t)4 * Tc * D_ * 8;
    double* pSq     = (double*)p; p += (size_t)4 * Tc * D_ * 8;
    float* hbuf     = (float*)p; p += (size_t)Tc * B_ * D_ * 4;
    float* scaleArr = (float*)p; p += (size_t)Tc * D_ * 4;
    float* shiftArr = (float*)p; p += (size_t)Tc * D_ * 4;
    float* sMem1    = (float*)p; p += (size_t)B_ * D_ * 4;
    float* sSpk1    = (float*)p; p += (size_t)B_ * D_ * 4;
    float* sMem2    = (float*)p; p += (size_t)B_ * O_ * 4;
    float* sSpk2    = (float*)p; p += (size_t)B_ * O_ * 4;
    float* cur2     = (float*)p; p += (size_t)Tc * B_ * O_ * 4;
    unsigned short* Wsp = (unsigned short*)p; p += (size_t)3 * D_ * D_ * 2;
    uint64* spkM    = (uint64*)p; p += (size_t)Tc * B_ * 8 * 8;

    presplitW_kernel<<<256, 256, 0, stream>>>(W1, Wsp);

    for (int t0 = 0; t0 < T_; t0 += Tc) {
        gemm1_kernel<<<Tc * 16, 256, 0, stream>>>(data, drop, Wsp, b1, hbuf,
                                                  pSum, pSq, t0, Tc);
        finalize_kernel<<<dim3(Tc, D_ / 256), 256, 0, stream>>>(
            pSum, pSq, gamma, bn_beta, scaleArr, shiftArr, Tc);
        scanA_kernel<<<(B_ * D_) / 256, 256, 0, stream>>>(hbuf, scaleArr, shiftArr, spkM,
                                                          sMem1, sSpk1, t0, Tc);
        gemm2_kernel<<<Tc * 16, 256, 0, stream>>>(spkM, W2, b2, cur2);
        scanB_kernel<<<20, 256, 0, stream>>>(cur2, out, sMem2, sSpk2, t0, Tc);
    }
}